// Round 8
// baseline (747.269 us; speedup 1.0000x reference)
//
#include <hip/hip_runtime.h>
#include <hip/hip_bf16.h>

// ---------------------------------------------------------------------------
// StreamingQwenMoE round 8: pre-dequant weights to f16 (one streaming pass)
// -> ALL GEMMs become pure-DMA m97-class loops (global_load_lds both operands,
// zero staging VALU, vmcnt(4) counted ledger, 1 barrier/tile).
// r7 diagnosis: fused-dequant reg-staging put ~160cyc of cvt+ds_write VALU in
// the serial path per K-tile (VALUBusy 20.5% > MfmaUtil 15.8%).
// ws: big path 269 MB (buffers aliased across sequential lifetimes), guarded
// by ws_size >= 270MB; else falls back to r7 path verbatim (681us).
// Verified carried: router/top8/dispatch, SwiGLU, C/D layout, XOR swizzle,
// bijective XCD swizzle, atomic-free pair-buffer combine, LDS<=81920 rule.
// ---------------------------------------------------------------------------

#define TT   2048
#define DD   2048
#define DFF  768
#define DSH  2048
#define EE   32
#define KTOP 8
#define CAP  1024

typedef _Float16 half8  __attribute__((ext_vector_type(8)));
typedef _Float16 half4v __attribute__((ext_vector_type(4)));
typedef float    f32x4  __attribute__((ext_vector_type(4)));

// ---------------- init ------------------------------------------------------
__global__ __launch_bounds__(256) void k_init(int* __restrict__ cnt,
                                              int* __restrict__ slot_tok) {
  int i = blockIdx.x * 256 + threadIdx.x;
  if (i < EE * CAP) slot_tok[i] = 0;
  if (i < EE) cnt[i] = 0;
}

// ---------------- f32 -> f16 cast -------------------------------------------
__global__ __launch_bounds__(256) void k_cast(const float* __restrict__ in,
                                              _Float16* __restrict__ out) {
  int i = blockIdx.x * 256 + threadIdx.x;
  float4 v = ((const float4*)in)[i];
  half4v h = { (_Float16)v.x, (_Float16)v.y, (_Float16)v.z, (_Float16)v.w };
  ((half4v*)out)[i] = h;
}

// ---------------- block-scale dequant, one row per block --------------------
// w: [E, M, N] f32, s: [E, M/128, N/128]; out f16. grid (M, E), block N/4.
template<int NCOLS>
__global__ void k_deq_row(const float* __restrict__ w, const float* __restrict__ s,
                          int mRows, _Float16* __restrict__ outp) {
  int r = blockIdx.x, e = blockIdx.y;
  int c4 = threadIdx.x;                       // float4 index in row
  long long base = ((long long)e * mRows + r) * NCOLS;
  float sc = s[(e * (mRows >> 7) + (r >> 7)) * (NCOLS >> 7) + (c4 >> 5)];
  float4 v = ((const float4*)(w + base))[c4];
  half4v h = { (_Float16)(v.x * sc), (_Float16)(v.y * sc),
               (_Float16)(v.z * sc), (_Float16)(v.w * sc) };
  ((half4v*)(outp + base))[c4] = h;
}

// ---------------- router: logits, top8, renorm, dispatch --------------------
__global__ __launch_bounds__(64) void k_router(
    const float* __restrict__ x, const float* __restrict__ rw,
    const float* __restrict__ wshg,
    float* __restrict__ shg, int* __restrict__ cnt,
    int* __restrict__ slot_tok, float* __restrict__ slot_w,
    int* __restrict__ slot_pair, int* __restrict__ pair_pos) {
  int t = blockIdx.x;
  int lane = threadIdx.x;
  const float* xr = x + (size_t)t * DD;
  float xv[32];
#pragma unroll
  for (int j = 0; j < 32; ++j) xv[j] = xr[lane + j * 64];

  __shared__ float lg[EE];
  for (int e = 0; e < EE; ++e) {
    const float* we = rw + (size_t)e * DD;
    float s = 0.f;
#pragma unroll
    for (int j = 0; j < 32; ++j) s += xv[j] * we[lane + j * 64];
#pragma unroll
    for (int off = 32; off > 0; off >>= 1) s += __shfl_down(s, off);
    if (lane == 0) lg[e] = s;
  }
  {
    float s = 0.f;
#pragma unroll
    for (int j = 0; j < 32; ++j) s += xv[j] * wshg[lane + j * 64];
#pragma unroll
    for (int off = 32; off > 0; off >>= 1) s += __shfl_down(s, off);
    if (lane == 0) shg[t] = 1.f / (1.f + expf(-s));
  }
  if (lane == 0) {
    unsigned used = 0;
    int sel[KTOP];
    float val[KTOP];
    for (int k = 0; k < KTOP; ++k) {
      float bv = -1e30f; int bi = 0;
      for (int e = 0; e < EE; ++e)
        if (!((used >> e) & 1) && lg[e] > bv) { bv = lg[e]; bi = e; }
      used |= (1u << bi);
      sel[k] = bi; val[k] = bv;
    }
    float mx = val[0], sum = 0.f;
    for (int k = 0; k < KTOP; ++k) { val[k] = expf(val[k] - mx); sum += val[k]; }
    float inv = 1.f / sum;
    for (int k = 0; k < KTOP; ++k) {
      int e = sel[k];
      int pos = atomicAdd(&cnt[e], 1);
      pair_pos[t * KTOP + k] = pos;
      if (pos < CAP) {
        slot_tok[e * CAP + pos] = t;
        slot_w[e * CAP + pos] = val[k] * inv;
        slot_pair[e * CAP + pos] = t * KTOP + k;
      }
    }
  }
}

// ======================= clean f16 GEMM (big-ws path) =======================
// C = A (rows x K, f16) * B (N x K, f16)^T. Both operands via global_load_lds
// (pre-swizzled source). sA[3] (A issued 2 ahead), sB[2] (B issued 1 ahead;
// B panel is L2-resident across same-XCD m-blocks). Uniform vmcnt(4).
// EPI: 0 = f16 OutH (SwiGLU if DUAL); 1 = f16 scatter w*val -> OutH[pair*DD];
//      2 = OutF[row] += shg[row]*val.
template<bool DUAL, bool GATHER, int EPI, int NPB, int MBB, int KDIM>
__global__ __launch_bounds__(256, 2) void k_gemm16(
    const _Float16* __restrict__ A,
    const _Float16* __restrict__ B0h, const _Float16* __restrict__ B1h,
    _Float16* __restrict__ OutH, float* __restrict__ OutF,
    const float* __restrict__ shg,
    int ldA, int ldOut,
    long long strideAE, long long strideBE, long long strideOE,
    const int* __restrict__ cnt, int rowsConst,
    const int* __restrict__ slot_tok, const float* __restrict__ slot_w) {
  constexpr int BK = 64;
  constexpr int KT = KDIM / BK;              // 32 / 12
  constexpr int NF = DUAL ? 2 : 4;
  constexpr int BN = DUAL ? 64 : 128;

  // bijective XCD swizzle
  const int f = blockIdx.x;
  const int xcd = f & 7;
  const int t0 = f >> 3;
  const int mb = t0 % MBB;
  const int pp = t0 / MBB;
  const int p  = pp * 8 + xcd;               // (NPB*E) % 8 == 0 for all uses
  const int nb = p % NPB;
  const int e  = p / NPB;

  int rows = cnt ? (cnt[e] > CAP ? CAP : cnt[e]) : rowsConst;
  const int rowBase = mb * 128;
  if (rowBase >= rows) return;
  const int nBase = nb * BN;

  const int tid = threadIdx.x;
  const int lane = tid & 63;
  const int wave = tid >> 6;
  const int wr = wave >> 1;
  const int wc = wave & 1;

  __shared__ __align__(16) _Float16 sA[3][8192];   // 48 KB
  __shared__ __align__(16) _Float16 sB[2][8192];   // 32 KB (total 81920 B)

  const _Float16* Ae = A + (GATHER ? 0 : (long long)e * strideAE);
  const _Float16* B0e = B0h + (long long)e * strideBE;
  const _Float16* B1e = DUAL ? (B1h + (long long)e * strideBE) : nullptr;

  // A staging: LDS dest linear, source col pre-swizzled (rule #21)
  int aByte[4];
#pragma unroll
  for (int i = 0; i < 4; ++i) {
    int c = tid + i * 256;                   // 16B chunk [0,1024)
    int row = c >> 3;                        // 0..127
    int colB = ((c & 7) << 4) ^ ((row & 7) << 4);
    int src = GATHER ? slot_tok[e * CAP + rowBase + row] : (rowBase + row);
    aByte[i] = src * (2 * ldA) + colB;
  }
  // B staging: same pattern; dual = [gate 64 rows][up 64 rows]
  int bByte[4];
#pragma unroll
  for (int i = 0; i < 4; ++i) {
    int c = tid + i * 256;
    int rn = DUAL ? ((c & 511) >> 3) : (c >> 3);
    int colB = ((c & 7) << 4) ^ ((rn & 7) << 4);
    bByte[i] = (nBase + rn) * (2 * KDIM) + colB;
  }

  f32x4 accG[4][NF];
  f32x4 accU[DUAL ? 4 : 1][NF];
#pragma unroll
  for (int m = 0; m < 4; ++m)
#pragma unroll
    for (int n = 0; n < NF; ++n) {
      accG[m][n] = (f32x4){0.f, 0.f, 0.f, 0.f};
      if constexpr (DUAL) accU[m][n] = (f32x4){0.f, 0.f, 0.f, 0.f};
    }

  auto stageA = [&](int kt, int buf) {       // 4 DMA
#pragma unroll
    for (int i = 0; i < 4; ++i) {
      __builtin_amdgcn_global_load_lds(
          (const __attribute__((address_space(1))) void*)
              ((const char*)Ae + aByte[i] + kt * 128),
          (__attribute__((address_space(3))) void*)&sA[buf][(tid + i * 256) * 8],
          16, 0, 0);
    }
  };
  auto stageB = [&](int kt, int buf) {       // 4 DMA (i>=2 -> up operand)
#pragma unroll
    for (int i = 0; i < 4; ++i) {
      const _Float16* src = (DUAL && i >= 2) ? B1e : B0e;
      __builtin_amdgcn_global_load_lds(
          (const __attribute__((address_space(1))) void*)
              ((const char*)src + bByte[i] + kt * 128),
          (__attribute__((address_space(3))) void*)&sB[buf][(tid + i * 256) * 8],
          16, 0, 0);
    }
  };
  auto computeTile = [&](int ia, int ib) {
    const char* pA = (const char*)&sA[ia][0];
    const char* pB = (const char*)&sB[ib][0];
#pragma unroll
    for (int kk = 0; kk < 2; ++kk) {
      const int koff = kk * 32 + (lane >> 4) * 8;    // f16 elems
      half8 a[4];
#pragma unroll
      for (int m = 0; m < 4; ++m) {
        int r = wr * 64 + m * 16 + (lane & 15);
        int byt = ((r << 7) + (koff << 1)) ^ ((r & 7) << 4);
        a[m] = *(const half8*)(pA + byt);
      }
      if constexpr (DUAL) {
        half8 bg[2], bu[2];
#pragma unroll
        for (int n = 0; n < 2; ++n) {
          int rn = wc * 32 + n * 16 + (lane & 15);
          int byt = ((rn << 7) + (koff << 1)) ^ ((rn & 7) << 4);
          bg[n] = *(const half8*)(pB + byt);
          bu[n] = *(const half8*)(pB + 8192 + byt);
        }
#pragma unroll
        for (int m = 0; m < 4; ++m)
#pragma unroll
          for (int n = 0; n < 2; ++n) {
            accG[m][n] = __builtin_amdgcn_mfma_f32_16x16x32_f16(a[m], bg[n], accG[m][n], 0, 0, 0);
            accU[m][n] = __builtin_amdgcn_mfma_f32_16x16x32_f16(a[m], bu[n], accU[m][n], 0, 0, 0);
          }
      } else {
        half8 b[4];
#pragma unroll
        for (int n = 0; n < 4; ++n) {
          int rn = wc * 64 + n * 16 + (lane & 15);
          int byt = ((rn << 7) + (koff << 1)) ^ ((rn & 7) << 4);
          b[n] = *(const half8*)(pB + byt);
        }
#pragma unroll
        for (int m = 0; m < 4; ++m)
#pragma unroll
          for (int n = 0; n < 4; ++n)
            accG[m][n] = __builtin_amdgcn_mfma_f32_16x16x32_f16(a[m], b[n], accG[m][n], 0, 0, 0);
      }
    }
  };

  // prologue: B(0), A(0), A(1) in flight (12 ops; pinned issue order)
  stageB(0, 0);
  __builtin_amdgcn_sched_barrier(0);
  stageA(0, 0);
  __builtin_amdgcn_sched_barrier(0);
  stageA(1, 1);
  __builtin_amdgcn_sched_barrier(0);

  int bufC = 0, bufW = 2;
  for (int kt = 0; kt < KT; ++kt) {
    // drain own ds_reads of compute(kt-1) before signaling the barrier
    asm volatile("s_waitcnt lgkmcnt(0)" ::: "memory");
    // B(kt),A(kt) landed when only the newest 4 ops (A(kt+1)) may be pending
    if (kt + 1 < KT) { asm volatile("s_waitcnt vmcnt(4)" ::: "memory"); }
    else             { asm volatile("s_waitcnt vmcnt(0)" ::: "memory"); }
    __builtin_amdgcn_sched_barrier(0);
    __builtin_amdgcn_s_barrier();
    __builtin_amdgcn_sched_barrier(0);
    if (kt + 1 < KT) stageB(kt + 1, (kt + 1) & 1);
    if (kt + 2 < KT) stageA(kt + 2, bufW);
    __builtin_amdgcn_sched_barrier(0);
    computeTile(bufC, kt & 1);
    bufC = (bufC == 2) ? 0 : bufC + 1;
    bufW = (bufW == 2) ? 0 : bufW + 1;
  }

  // epilogue; C/D layout: col = lane&15, row = (lane>>4)*4 + i (verified)
#pragma unroll
  for (int m = 0; m < 4; ++m) {
#pragma unroll
    for (int i = 0; i < 4; ++i) {
      int row = rowBase + wr * 64 + m * 16 + (lane >> 4) * 4 + i;
      if (row < rows) {
        if constexpr (EPI == 1) {
          int pair = slot_tok[e * CAP + row];
          float w = slot_w[e * CAP + row];
#pragma unroll
          for (int n = 0; n < NF; ++n) {
            int col = nBase + wc * 64 + n * 16 + (lane & 15);
            OutH[(long long)pair * DD + col] = (_Float16)(w * accG[m][n][i]);
          }
        } else if constexpr (EPI == 2) {
          float g = shg[row];
#pragma unroll
          for (int n = 0; n < NF; ++n) {
            int col = nBase + wc * 64 + n * 16 + (lane & 15);
            OutF[(long long)row * DD + col] += g * accG[m][n][i];
          }
        } else {
          long long outBase = (long long)e * strideOE;
#pragma unroll
          for (int n = 0; n < NF; ++n) {
            int col = nBase + (DUAL ? wc * 32 : wc * 64) + n * 16 + (lane & 15);
            long long o = outBase + (long long)row * ldOut + col;
            if constexpr (DUAL) {
              float gv = accG[m][n][i];
              float uv = accU[m][n][i];
              OutH[o] = (_Float16)((gv / (1.f + __expf(-gv))) * uv);
            } else {
              OutH[o] = (_Float16)accG[m][n][i];
            }
          }
        }
      }
    }
  }
}

// ======================= r7 fused-dequant GEMM (fallback) ===================
template<bool DUAL, bool GATHER, bool DEQ, int EPI, int NPB, int MBB, int KDIM>
__global__ __launch_bounds__(256, 2) void k_gemm(
    const _Float16* __restrict__ A,
    const float* __restrict__ B0f, const float* __restrict__ B1f,
    const float* __restrict__ S0, const float* __restrict__ S1,
    int sCols, int sStrideE,
    _Float16* __restrict__ OutH, float* __restrict__ OutF,
    const float* __restrict__ shg,
    int ldA, int ldOut,
    long long strideAE, long long strideBE, long long strideOE,
    const int* __restrict__ cnt, int rowsConst,
    const int* __restrict__ slot_tok, const float* __restrict__ slot_w) {
  constexpr int BK = 64;
  constexpr int KT = KDIM / BK;
  constexpr int NF = DUAL ? 2 : 4;
  constexpr int BN = DUAL ? 64 : 128;
  constexpr int BCH = DUAL ? 4 : 8;

  const int f = blockIdx.x;
  const int xcd = f & 7;
  const int t0 = f >> 3;
  const int mb = t0 % MBB;
  const int pp = t0 / MBB;
  const int p  = pp * 8 + xcd;
  const int nb = p % NPB;
  const int e  = p / NPB;

  int rows = cnt ? (cnt[e] > CAP ? CAP : cnt[e]) : rowsConst;
  const int rowBase = mb * 128;
  if (rowBase >= rows) return;
  const int nBase = nb * BN;

  const int tid = threadIdx.x;
  const int lane = tid & 63;
  const int wave = tid >> 6;
  const int wr = wave >> 1;
  const int wc = wave & 1;

  __shared__ __align__(16) _Float16 sA[3][8192];
  __shared__ __align__(16) _Float16 sB[2][8192];

  const _Float16* Ae = A + (GATHER ? 0 : (long long)e * strideAE);
  const float* B0e = B0f + (long long)e * strideBE;
  const float* B1e = DUAL ? (B1f + (long long)e * strideBE) : nullptr;
  const float* S0e = DEQ ? (S0 + (long long)e * sStrideE) : nullptr;
  const float* S1e = (DEQ && DUAL) ? (S1 + (long long)e * sStrideE) : nullptr;
  const int sRow = DEQ ? (nBase >> 7) * sCols : 0;

  int aByte[4];
#pragma unroll
  for (int i = 0; i < 4; ++i) {
    int c = tid + i * 256;
    int row = c >> 3;
    int colB = ((c & 7) << 4) ^ ((row & 7) << 4);
    int src = GATHER ? slot_tok[e * CAP + rowBase + row] : (rowBase + row);
    aByte[i] = src * (2 * ldA) + colB;
  }
  int bOff[BCH], wByte[BCH];
#pragma unroll
  for (int i = 0; i < BCH; ++i) {
    int c = tid + i * 256;
    int rn = c >> 4;
    int c4 = (c & 15) << 2;
    bOff[i] = (nBase + rn) * KDIM + c4;
    wByte[i] = ((rn << 7) + (c4 << 1)) ^ ((rn & 7) << 4);
  }

  f32x4 accG[4][NF];
  f32x4 accU[DUAL ? 4 : 1][NF];
#pragma unroll
  for (int m = 0; m < 4; ++m)
#pragma unroll
    for (int n = 0; n < NF; ++n) {
      accG[m][n] = (f32x4){0.f, 0.f, 0.f, 0.f};
      if constexpr (DUAL) accU[m][n] = (f32x4){0.f, 0.f, 0.f, 0.f};
    }

  auto stageA = [&](int kt, int buf) {
#pragma unroll
    for (int i = 0; i < 4; ++i) {
      __builtin_amdgcn_global_load_lds(
          (const __attribute__((address_space(1))) void*)
              ((const char*)Ae + aByte[i] + kt * (BK * 2)),
          (__attribute__((address_space(3))) void*)&sA[buf][(tid + i * 256) * 8],
          16, 0, 0);
    }
  };
  auto loadB = [&](int kt, float4 (&r0)[BCH], float4 (&r1)[BCH]) {
    const int ko = kt * BK;
#pragma unroll
    for (int i = 0; i < BCH; ++i) r0[i] = *(const float4*)(B0e + bOff[i] + ko);
    if constexpr (DUAL) {
#pragma unroll
      for (int i = 0; i < BCH; ++i) r1[i] = *(const float4*)(B1e + bOff[i] + ko);
    }
  };
  auto storeB = [&](int kt, float4 (&r0)[BCH], float4 (&r1)[BCH]) {
    float s0 = 1.f, s1 = 1.f;
    if constexpr (DEQ) {
      s0 = S0e[sRow + (kt >> 1)];
      if constexpr (DUAL) s1 = S1e[sRow + (kt >> 1)];
    }
    char* base = (char*)&sB[kt & 1][0];
#pragma unroll
    for (int i = 0; i < BCH; ++i) {
      half4v h = { (_Float16)(r0[i].x * s0), (_Float16)(r0[i].y * s0),
                   (_Float16)(r0[i].z * s0), (_Float16)(r0[i].w * s0) };
      *(half4v*)(base + wByte[i]) = h;
      if constexpr (DUAL) {
        half4v h1 = { (_Float16)(r1[i].x * s1), (_Float16)(r1[i].y * s1),
                      (_Float16)(r1[i].z * s1), (_Float16)(r1[i].w * s1) };
        *(half4v*)(base + 8192 + wByte[i]) = h1;
      }
    }
  };
  auto computeTile = [&](int ia, int ib) {
    const char* pA = (const char*)&sA[ia][0];
    const char* pB = (const char*)&sB[ib][0];
#pragma unroll
    for (int kk = 0; kk < 2; ++kk) {
      const int koff = kk * 32 + (lane >> 4) * 8;
      half8 a[4];
#pragma unroll
      for (int m = 0; m < 4; ++m) {
        int r = wr * 64 + m * 16 + (lane & 15);
        int byt = ((r << 7) + (koff << 1)) ^ ((r & 7) << 4);
        a[m] = *(const half8*)(pA + byt);
      }
      if constexpr (DUAL) {
        half8 bg[2], bu[2];
#pragma unroll
        for (int n = 0; n < 2; ++n) {
          int rn = wc * 32 + n * 16 + (lane & 15);
          int byt = ((rn << 7) + (koff << 1)) ^ ((rn & 7) << 4);
          bg[n] = *(const half8*)(pB + byt);
          bu[n] = *(const half8*)(pB + 8192 + byt);
        }
#pragma unroll
        for (int m = 0; m < 4; ++m)
#pragma unroll
          for (int n = 0; n < 2; ++n) {
            accG[m][n] = __builtin_amdgcn_mfma_f32_16x16x32_f16(a[m], bg[n], accG[m][n], 0, 0, 0);
            accU[m][n] = __builtin_amdgcn_mfma_f32_16x16x32_f16(a[m], bu[n], accU[m][n], 0, 0, 0);
          }
      } else {
        half8 b[4];
#pragma unroll
        for (int n = 0; n < 4; ++n) {
          int rn = wc * 64 + n * 16 + (lane & 15);
          int byt = ((rn << 7) + (koff << 1)) ^ ((rn & 7) << 4);
          b[n] = *(const half8*)(pB + byt);
        }
#pragma unroll
        for (int m = 0; m < 4; ++m)
#pragma unroll
          for (int n = 0; n < 4; ++n)
            accG[m][n] = __builtin_amdgcn_mfma_f32_16x16x32_f16(a[m], b[n], accG[m][n], 0, 0, 0);
      }
    }
  };

  float4 rbE0[BCH], rbE1[BCH], rbO0[BCH], rbO1[BCH];

  stageA(0, 0); loadB(0, rbE0, rbE1);
  __builtin_amdgcn_sched_barrier(0);
  stageA(1, 1); loadB(1, rbO0, rbO1);
  __builtin_amdgcn_sched_barrier(0);

  int bufC = 0, bufW = 2;

  for (int kt = 0; kt < KT; kt += 2) {
    if (kt + 1 < KT) { asm volatile("s_waitcnt vmcnt(12)" ::: "memory"); }
    else             { asm volatile("s_waitcnt vmcnt(0)"  ::: "memory"); }
    __builtin_amdgcn_sched_barrier(0);
    storeB(kt, rbE0, rbE1);
    asm volatile("s_waitcnt lgkmcnt(0)" ::: "memory");
    __builtin_amdgcn_sched_barrier(0);
    __builtin_amdgcn_s_barrier();
    __builtin_amdgcn_sched_barrier(0);
    if (kt + 2 < KT) { stageA(kt + 2, bufW); loadB(kt + 2, rbE0, rbE1); }
    __builtin_amdgcn_sched_barrier(0);
    computeTile(bufC, 0);
    bufC = (bufC == 2) ? 0 : bufC + 1;
    bufW = (bufW == 2) ? 0 : bufW + 1;

    if (kt + 2 < KT) { asm volatile("s_waitcnt vmcnt(12)" ::: "memory"); }
    else             { asm volatile("s_waitcnt vmcnt(0)"  ::: "memory"); }
    __builtin_amdgcn_sched_barrier(0);
    storeB(kt + 1, rbO0, rbO1);
    asm volatile("s_waitcnt lgkmcnt(0)" ::: "memory");
    __builtin_amdgcn_sched_barrier(0);
    __builtin_amdgcn_s_barrier();
    __builtin_amdgcn_sched_barrier(0);
    if (kt + 3 < KT) { stageA(kt + 3, bufW); loadB(kt + 3, rbO0, rbO1); }
    __builtin_amdgcn_sched_barrier(0);
    computeTile(bufC, 1);
    bufC = (bufC == 2) ? 0 : bufC + 1;
    bufW = (bufW == 2) ? 0 : bufW + 1;
  }

#pragma unroll
  for (int m = 0; m < 4; ++m) {
#pragma unroll
    for (int i = 0; i < 4; ++i) {
      int row = rowBase + wr * 64 + m * 16 + (lane >> 4) * 4 + i;
      if (row < rows) {
        if constexpr (EPI == 1) {
          int pair = slot_tok[e * CAP + row];
          float w = slot_w[e * CAP + row];
#pragma unroll
          for (int n = 0; n < NF; ++n) {
            int col = nBase + wc * 64 + n * 16 + (lane & 15);
            OutH[(long long)pair * DD + col] = (_Float16)(w * accG[m][n][i]);
          }
        } else if constexpr (EPI == 2) {
          float g = shg[row];
#pragma unroll
          for (int n = 0; n < NF; ++n) {
            int col = nBase + wc * 64 + n * 16 + (lane & 15);
            OutF[(long long)row * DD + col] += g * accG[m][n][i];
          }
        } else {
          long long outBase = (long long)e * strideOE;
#pragma unroll
          for (int n = 0; n < NF; ++n) {
            int col = nBase + (DUAL ? wc * 32 : wc * 64) + n * 16 + (lane & 15);
            long long o = outBase + (long long)row * ldOut + col;
            if constexpr (DUAL) {
              float gv = accG[m][n][i];
              float uv = accU[m][n][i];
              OutH[o] = (_Float16)((gv / (1.f + __expf(-gv))) * uv);
            } else {
              OutH[o] = (_Float16)accG[m][n][i];
            }
          }
        }
      }
    }
  }
}

// ---------------- combine: out[t] = sum_k (pos<CAP) Yp[t*8+k] ----------------
__global__ __launch_bounds__(256) void k_combine(
    const _Float16* __restrict__ Yp, const int* __restrict__ pair_pos,
    float* __restrict__ out) {
  int t = blockIdx.x;
  int col = threadIdx.x * 8;
  float acc[8] = {0.f, 0.f, 0.f, 0.f, 0.f, 0.f, 0.f, 0.f};
#pragma unroll
  for (int k = 0; k < KTOP; ++k) {
    if (pair_pos[t * KTOP + k] < CAP) {
      half8 y = *(const half8*)&Yp[((size_t)t * KTOP + k) * DD + col];
#pragma unroll
      for (int j = 0; j < 8; ++j) acc[j] += (float)y[j];
    }
  }
  float4 o0 = {acc[0], acc[1], acc[2], acc[3]};
  float4 o1 = {acc[4], acc[5], acc[6], acc[7]};
  *(float4*)&out[(size_t)t * DD + col] = o0;
  *(float4*)&out[(size_t)t * DD + col + 4] = o1;
}

// ---------------------------------------------------------------------------
extern "C" void kernel_launch(void* const* d_in, const int* in_sizes, int n_in,
                              void* d_out, int out_size, void* d_ws, size_t ws_size,
                              hipStream_t stream) {
  (void)in_sizes; (void)n_in; (void)out_size;
  const float* x    = (const float*)d_in[0];
  const float* rw   = (const float*)d_in[1];
  const float* wg   = (const float*)d_in[2];
  const float* sg   = (const float*)d_in[3];
  const float* wu   = (const float*)d_in[4];
  const float* su   = (const float*)d_in[5];
  const float* wd   = (const float*)d_in[6];
  const float* sd   = (const float*)d_in[7];
  const float* wsg  = (const float*)d_in[8];
  const float* wsu  = (const float*)d_in[9];
  const float* wsd  = (const float*)d_in[10];
  const float* wshg = (const float*)d_in[11];
  float* out = (float*)d_out;

  char* p = (char*)d_ws;
  auto alloc = [&](size_t bytes) {
    char* r = p;
    p += (bytes + 255) & ~(size_t)255;
    return r;
  };

  const bool big = ws_size >= (size_t)270 * 1000 * 1000;

  if (big) {
    // ---- big path: pre-dequant to f16, clean DMA GEMMs (aliased buffers) ----
    _Float16* x_h  = (_Float16*)alloc((size_t)TT * DD * 2);           //  8.4 MB
    _Float16* bufA = (_Float16*)alloc((size_t)EE * DFF * DD * 2);     // 100.7 MB: wg_h -> wd_h
    _Float16* bufB = (_Float16*)alloc((size_t)EE * DFF * DD * 2);     // 100.7 MB: wu_h -> Yp
    _Float16* bufH = (_Float16*)alloc((size_t)EE * CAP * DFF * 2);    //  50.3 MB: H -> ws*_h
    _Float16* Hsh  = (_Float16*)alloc((size_t)TT * DSH * 2);          //   8.4 MB
    float* shg     = (float*)alloc((size_t)TT * 4);
    int* cnt       = (int*)alloc((size_t)EE * 4);
    int* slot_tok  = (int*)alloc((size_t)EE * CAP * 4);
    float* slot_w  = (float*)alloc((size_t)EE * CAP * 4);
    int* slot_pair = (int*)alloc((size_t)EE * CAP * 4);
    int* pair_pos  = (int*)alloc((size_t)TT * KTOP * 4);

    _Float16* Yp    = bufB;                  // alias (wu_h dead after gate+up)
    _Float16* wsg_h = bufH;                  // alias (H dead after down)
    _Float16* wsu_h = bufH + (size_t)TT * DD;
    _Float16* wsd_h = bufH + (size_t)2 * TT * DD;

    k_init<<<(EE * CAP + 255) / 256, 256, 0, stream>>>(cnt, slot_tok);
    k_cast<<<(TT * DD / 4) / 256, 256, 0, stream>>>(x, x_h);
    k_router<<<TT, 64, 0, stream>>>(x, rw, wshg, shg, cnt, slot_tok, slot_w,
                                    slot_pair, pair_pos);

    // dequant routed weights (f32*scale -> f16)
    k_deq_row<DD><<<dim3(DFF, EE), DD / 4, 0, stream>>>(wg, sg, DFF, bufA);
    k_deq_row<DD><<<dim3(DFF, EE), DD / 4, 0, stream>>>(wu, su, DFF, bufB);

    // routed gate+up -> H
    k_gemm16<true, true, 0, 12, 8, DD><<<3072, 256, 0, stream>>>(
        x_h, bufA, bufB, bufH, nullptr, nullptr,
        DD, DFF, 0LL, (long long)DFF * DD, (long long)CAP * DFF,
        cnt, 0, slot_tok, nullptr);

    // dequant wd over wg_h region (dead), then down -> Yp (over wu_h, dead)
    k_deq_row<DFF><<<dim3(DD, EE), DFF / 4, 0, stream>>>(wd, sd, DD, bufA);
    k_gemm16<false, false, 1, 16, 8, DFF><<<4096, 256, 0, stream>>>(
        bufH, bufA, bufA, Yp, nullptr, nullptr,
        DFF, DD, (long long)CAP * DFF, (long long)DD * DFF, 0LL,
        cnt, 0, slot_pair, slot_w);

    k_combine<<<TT, 256, 0, stream>>>(Yp, pair_pos, out);

    // shared weights -> f16 (into H region, dead), then shared GEMMs
    k_cast<<<(DD * DSH / 4) / 256, 256, 0, stream>>>(wsg, wsg_h);
    k_cast<<<(DD * DSH / 4) / 256, 256, 0, stream>>>(wsu, wsu_h);
    k_cast<<<(DD * DSH / 4) / 256, 256, 0, stream>>>(wsd, wsd_h);

    k_gemm16<true, false, 0, 32, 16, DD><<<512, 256, 0, stream>>>(
        x_h, wsg_h, wsu_h, Hsh, nullptr, nullptr,
        DD, DSH, 0LL, 0LL, 0LL,
        nullptr, TT, nullptr, nullptr);

    k_gemm16<false, false, 2, 16, 16, DSH><<<256, 256, 0, stream>>>(
        Hsh, wsd_h, wsd_h, nullptr, out, shg,
        DSH, DD, 0LL, 0LL, 0LL,
        nullptr, TT, nullptr, nullptr);
  } else {
    // ---- fallback: r7 path verbatim (681 us) ----
    _Float16* x_h   = (_Float16*)alloc((size_t)TT * DD * 2);
    _Float16* H     = (_Float16*)alloc((size_t)EE * CAP * DFF * 2);
    _Float16* Hsh   = (_Float16*)alloc((size_t)TT * DSH * 2);
    _Float16* Yp    = (_Float16*)alloc((size_t)TT * KTOP * DD * 2);
    float* shg      = (float*)alloc((size_t)TT * 4);
    int* cnt        = (int*)alloc((size_t)EE * 4);
    int* slot_tok   = (int*)alloc((size_t)EE * CAP * 4);
    float* slot_w   = (float*)alloc((size_t)EE * CAP * 4);
    int* slot_pair  = (int*)alloc((size_t)EE * CAP * 4);
    int* pair_pos   = (int*)alloc((size_t)TT * KTOP * 4);

    k_init<<<(EE * CAP + 255) / 256, 256, 0, stream>>>(cnt, slot_tok);
    k_cast<<<(TT * DD / 4) / 256, 256, 0, stream>>>(x, x_h);
    k_router<<<TT, 64, 0, stream>>>(x, rw, wshg, shg, cnt, slot_tok, slot_w,
                                    slot_pair, pair_pos);

    k_gemm<true, true, true, 0, 12, 8, DD><<<3072, 256, 0, stream>>>(
        x_h, wg, wu, sg, su, DD / 128, (DFF / 128) * (DD / 128),
        H, nullptr, nullptr,
        DD, DFF, 0LL, (long long)DFF * DD, (long long)CAP * DFF,
        cnt, 0, slot_tok, nullptr);

    k_gemm<false, false, true, 1, 16, 8, DFF><<<4096, 256, 0, stream>>>(
        H, wd, wd, sd, sd, DFF / 128, (DD / 128) * (DFF / 128),
        Yp, nullptr, nullptr,
        DFF, DD, (long long)CAP * DFF, (long long)DD * DFF, 0LL,
        cnt, 0, slot_pair, slot_w);

    k_combine<<<TT, 256, 0, stream>>>(Yp, pair_pos, out);

    k_gemm<true, false, false, 0, 32, 16, DD><<<512, 256, 0, stream>>>(
        x_h, wsg, wsu, nullptr, nullptr, 0, 0,
        Hsh, nullptr, nullptr,
        DD, DSH, 0LL, 0LL, 0LL,
        nullptr, TT, nullptr, nullptr);

    k_gemm<false, false, false, 2, 16, 16, DSH><<<256, 256, 0, stream>>>(
        Hsh, wsd, wsd, nullptr, nullptr, 0, 0,
        nullptr, out, shg,
        DSH, DD, 0LL, 0LL, 0LL,
        nullptr, TT, nullptr, nullptr);
  }
}